// Round 1
// baseline (294.660 us; speedup 1.0000x reference)
//
#include <hip/hip_runtime.h>
#include <math.h>

#define NN 32
#define CC 512
#define PP 1024   // H*W
#define KK 64
static constexpr float EPS = 1e-12f;

// ---------------- transpose conv_w [K][C] -> wT [C][K] ----------------
__global__ void k_transpose_w(const float* __restrict__ w, float* __restrict__ wT) {
    int i = blockIdx.x * 256 + threadIdx.x;   // over C*K = 32768
    if (i >= CC * KK) return;
    int c = i >> 6, k = i & 63;
    wT[i] = w[k * CC + c];
}

// ---------------- per-pixel inverse L2 norm over channels ----------------
// grid: N*16 blocks (64 pixels each), 256 threads (4 c-groups x 64 pixels)
__global__ void k_pixnorm(const float* __restrict__ x, float* __restrict__ inv_n) {
    int b = blockIdx.x;
    int n = b >> 4;
    int p0 = (b & 15) << 6;
    int pix = threadIdx.x & 63;
    int cg = threadIdx.x >> 6;
    const float* xp = x + ((size_t)n * CC) * PP + p0 + pix;
    float s = 0.f;
    int cbeg = cg * 128;
#pragma unroll 4
    for (int c = cbeg; c < cbeg + 128; ++c) {
        float v = xp[(size_t)c * PP];
        s = fmaf(v, v, s);
    }
    __shared__ float red[4][64];
    red[cg][pix] = s;
    __syncthreads();
    if (threadIdx.x < 64) {
        float t = red[0][pix] + red[1][pix] + red[2][pix] + red[3][pix];
        inv_n[n * PP + p0 + pix] = 1.0f / fmaxf(sqrtf(t), EPS);
    }
}

// ---------------- logits + softmax over K -> sa [N][K][P] ----------------
// grid: N*16 blocks (64 pixels each), 256 threads (4 k-groups of 16 k's x 64 pixels)
__global__ void k_softmax(const float* __restrict__ x, const float* __restrict__ wT,
                          const float* __restrict__ bias, const float* __restrict__ inv_n,
                          float* __restrict__ sa) {
    int b = blockIdx.x;
    int n = b >> 4;
    int p0 = (b & 15) << 6;
    int pix = threadIdx.x & 63;
    int kg = __builtin_amdgcn_readfirstlane(threadIdx.x >> 6);   // wave-uniform 0..3
    const float* xp = x + ((size_t)n * CC) * PP + p0 + pix;
    float inv = inv_n[n * PP + p0 + pix];

    float acc[16];
#pragma unroll
    for (int j = 0; j < 16; ++j) acc[j] = 0.f;

    const float* wp = wT + kg * 16;
    for (int c = 0; c < CC; ++c) {
        float xv = xp[(size_t)c * PP];
#pragma unroll
        for (int j = 0; j < 16; ++j) acc[j] = fmaf(wp[c * KK + j], xv, acc[j]);
    }

    float l[16];
    float m = -1e30f;
#pragma unroll
    for (int j = 0; j < 16; ++j) {
        l[j] = fmaf(acc[j], inv, bias[kg * 16 + j]);
        m = fmaxf(m, l[j]);
    }

    __shared__ float red[4][64];
    red[kg][pix] = m;
    __syncthreads();
    m = fmaxf(fmaxf(red[0][pix], red[1][pix]), fmaxf(red[2][pix], red[3][pix]));

    float e[16];
    float s = 0.f;
#pragma unroll
    for (int j = 0; j < 16; ++j) {
        e[j] = __expf(l[j] - m);
        s += e[j];
    }
    __syncthreads();
    red[kg][pix] = s;
    __syncthreads();
    s = red[0][pix] + red[1][pix] + red[2][pix] + red[3][pix];
    float si = 1.0f / s;

    float* sp = sa + (size_t)n * KK * PP + (size_t)(kg * 16) * PP + p0 + pix;
#pragma unroll
    for (int j = 0; j < 16; ++j) sp[(size_t)j * PP] = e[j] * si;
}

// ---------------- S[n][k] = sum_p sa ----------------
// grid: N*K/4 blocks, 256 threads, one wave per row
__global__ void k_srow(const float* __restrict__ sa, float* __restrict__ S) {
    int r = blockIdx.x * 4 + (threadIdx.x >> 6);
    int lane = threadIdx.x & 63;
    const float* sp = sa + (size_t)r * PP + lane;
    float s = 0.f;
#pragma unroll
    for (int i = 0; i < PP / 64; ++i) s += sp[i * 64];
#pragma unroll
    for (int off = 32; off > 0; off >>= 1) s += __shfl_xor(s, off);
    if (lane == 0) S[r] = s;
}

// ---------------- vlad[n][k][c] = sum_p sa*xnorm - S*cent ----------------
// grid: N*8 blocks (full K=64 x 64-wide C tile), 256 threads
__global__ void __launch_bounds__(256) k_vlad(const float* __restrict__ x, const float* __restrict__ sa,
                       const float* __restrict__ inv_n, const float* __restrict__ S,
                       const float* __restrict__ cent, float* __restrict__ vlad) {
    int n = blockIdx.x >> 3;
    int c0 = (blockIdx.x & 7) << 6;
    __shared__ float sa_s[32][68];
    __shared__ float x_s[32][68];
    int tid = threadIdx.x;
    int kq = (tid & 15) << 2;
    int cq = (tid >> 4) << 2;
    float acc[4][4] = {};
    const float* xb = x + ((size_t)n * CC + c0) * PP;
    const float* sb = sa + (size_t)n * KK * PP;
    const float* ib = inv_n + n * PP;

    for (int pt = 0; pt < PP; pt += 32) {
        __syncthreads();
        for (int i = tid; i < 2048; i += 256) {
            int k = i >> 5, p = i & 31;
            sa_s[p][k] = sb[(size_t)k * PP + pt + p];
        }
        for (int i = tid; i < 2048; i += 256) {
            int c = i >> 5, p = i & 31;
            x_s[p][c] = xb[(size_t)c * PP + pt + p] * ib[pt + p];
        }
        __syncthreads();
#pragma unroll 4
        for (int p = 0; p < 32; ++p) {
            float4 a = *(const float4*)&sa_s[p][kq];
            float4 bb = *(const float4*)&x_s[p][cq];
            float av[4] = {a.x, a.y, a.z, a.w};
            float bv[4] = {bb.x, bb.y, bb.z, bb.w};
#pragma unroll
            for (int i = 0; i < 4; ++i)
#pragma unroll
                for (int j = 0; j < 4; ++j)
                    acc[i][j] = fmaf(av[i], bv[j], acc[i][j]);
        }
    }

#pragma unroll
    for (int kk = 0; kk < 4; ++kk) {
        float sv = S[n * KK + kq + kk];
        const float* cp = &cent[(size_t)(kq + kk) * CC + c0 + cq];
        float4 cv = *(const float4*)cp;
        float4 o;
        o.x = fmaf(-sv, cv.x, acc[kk][0]);
        o.y = fmaf(-sv, cv.y, acc[kk][1]);
        o.z = fmaf(-sv, cv.z, acc[kk][2]);
        o.w = fmaf(-sv, cv.w, acc[kk][3]);
        *(float4*)&vlad[((size_t)n * KK + kq + kk) * CC + c0 + cq] = o;
    }
}

// ---------------- per-row (n,k) sumsq + inv norm ----------------
__global__ void k_rownorm(const float* __restrict__ vlad, float* __restrict__ rinv,
                          float* __restrict__ rsq) {
    int r = blockIdx.x * 4 + (threadIdx.x >> 6);
    int lane = threadIdx.x & 63;
    const float* vp = vlad + (size_t)r * CC + lane;
    float s = 0.f;
#pragma unroll
    for (int i = 0; i < CC / 64; ++i) {
        float v = vp[i * 64];
        s = fmaf(v, v, s);
    }
#pragma unroll
    for (int off = 32; off > 0; off >>= 1) s += __shfl_xor(s, off);
    if (lane == 0) {
        float iv = 1.0f / fmaxf(sqrtf(s), EPS);
        rinv[r] = iv;
        rsq[r] = s * iv * iv;   // contribution of normalized row to global sumsq
    }
}

// ---------------- per-n total inverse norm ----------------
__global__ void k_tot(const float* __restrict__ rsq, float* __restrict__ tinv) {
    int n = blockIdx.x;
    int lane = threadIdx.x;   // 64 threads
    float s = rsq[n * KK + lane];
#pragma unroll
    for (int off = 32; off > 0; off >>= 1) s += __shfl_xor(s, off);
    if (lane == 0) tinv[n] = 1.0f / fmaxf(sqrtf(s), EPS);
}

// ---------------- final scale ----------------
__global__ void k_final(const float* __restrict__ vlad, const float* __restrict__ rinv,
                        const float* __restrict__ tinv, float* __restrict__ out) {
    size_t i4 = (size_t)blockIdx.x * 256 + threadIdx.x;   // over 262144 float4s
    float4 v = ((const float4*)vlad)[i4];
    int row = (int)(i4 >> 7);          // (i4*4) / 512
    int n = row >> 6;
    float sc = rinv[row] * tinv[n];
    float4 o{v.x * sc, v.y * sc, v.z * sc, v.w * sc};
    ((float4*)out)[i4] = o;
}

extern "C" void kernel_launch(void* const* d_in, const int* in_sizes, int n_in,
                              void* d_out, int out_size, void* d_ws, size_t ws_size,
                              hipStream_t stream) {
    const float* x    = (const float*)d_in[0];
    const float* w    = (const float*)d_in[1];
    const float* bias = (const float*)d_in[2];
    const float* cent = (const float*)d_in[3];
    float* ws = (float*)d_ws;

    float* inv_n = ws;                   // 32768
    float* sa    = inv_n + NN * PP;      // 2097152
    float* S     = sa + (size_t)NN * KK * PP;  // 2048
    float* vlad  = S + NN * KK;          // 1048576
    float* rinv  = vlad + (size_t)NN * KK * CC; // 2048
    float* rsq   = rinv + NN * KK;       // 2048
    float* tinv  = rsq + NN * KK;        // 32
    float* wT    = tinv + NN;            // 32768

    float* out = (float*)d_out;

    k_transpose_w<<<dim3(128), dim3(256), 0, stream>>>(w, wT);
    k_pixnorm<<<dim3(NN * 16), dim3(256), 0, stream>>>(x, inv_n);
    k_softmax<<<dim3(NN * 16), dim3(256), 0, stream>>>(x, wT, bias, inv_n, sa);
    k_srow<<<dim3(NN * KK / 4), dim3(256), 0, stream>>>(sa, S);
    k_vlad<<<dim3(NN * 8), dim3(256), 0, stream>>>(x, sa, inv_n, S, cent, vlad);
    k_rownorm<<<dim3(NN * KK / 4), dim3(256), 0, stream>>>(vlad, rinv, rsq);
    k_tot<<<dim3(NN), dim3(64), 0, stream>>>(rsq, tinv);
    k_final<<<dim3(1024), dim3(256), 0, stream>>>(vlad, rinv, tinv, out);
}

// Round 2
// 117.043 us; speedup vs baseline: 2.5175x; 2.5175x over previous
//
#include <hip/hip_runtime.h>
#include <math.h>

#define NN 32
#define CC 512
#define PP 1024   // H*W
#define KK 64
static constexpr float EPS = 1e-12f;

// ---------------- transpose conv_w [K][C] -> wT [C][K] ----------------
__global__ void k_transpose_w(const float* __restrict__ w, float* __restrict__ wT) {
    int i = blockIdx.x * 256 + threadIdx.x;   // over C*K = 32768
    if (i >= CC * KK) return;
    int c = i >> 6, k = i & 63;
    wT[i] = w[k * CC + c];
}

// ---------------- fused pixnorm + logits + softmax over K -> sa [N][K][P] ----------------
// grid: N*16 blocks (64 pixels each), 512 threads (8 k-groups of 8 k's x 64 pixels)
__global__ void __launch_bounds__(512) k_softmax(
        const float* __restrict__ x, const float* __restrict__ wT,
        const float* __restrict__ bias, float* __restrict__ inv_n,
        float* __restrict__ sa) {
    int b = blockIdx.x;
    int n = b >> 4;
    int p0 = (b & 15) << 6;
    int pix = threadIdx.x & 63;
    int kg = __builtin_amdgcn_readfirstlane(threadIdx.x >> 6);   // wave-uniform 0..7
    const float* xp = x + ((size_t)n * CC) * PP + p0 + pix;

    __shared__ float red[8][64];

    // phase 1: per-pixel sumsq over C, split across the 8 waves
    float s = 0.f;
#pragma unroll 4
    for (int c = kg * 64; c < kg * 64 + 64; ++c) {
        float v = xp[(size_t)c * PP];
        s = fmaf(v, v, s);
    }
    red[kg][pix] = s;
    __syncthreads();
    float tot = 0.f;
#pragma unroll
    for (int g = 0; g < 8; ++g) tot += red[g][pix];
    float inv = 1.0f / fmaxf(sqrtf(tot), EPS);
    if (kg == 0) inv_n[n * PP + p0 + pix] = inv;

    // phase 2: logits for this wave's 8 clusters
    float acc[8];
#pragma unroll
    for (int j = 0; j < 8; ++j) acc[j] = 0.f;
    const float* wp = wT + kg * 8;
    for (int c = 0; c < CC; ++c) {
        float xv = xp[(size_t)c * PP];
#pragma unroll
        for (int j = 0; j < 8; ++j) acc[j] = fmaf(wp[c * KK + j], xv, acc[j]);
    }

    float l[8];
    float m = -1e30f;
#pragma unroll
    for (int j = 0; j < 8; ++j) {
        l[j] = fmaf(acc[j], inv, bias[kg * 8 + j]);
        m = fmaxf(m, l[j]);
    }

    __syncthreads();
    red[kg][pix] = m;
    __syncthreads();
    m = -1e30f;
#pragma unroll
    for (int g = 0; g < 8; ++g) m = fmaxf(m, red[g][pix]);

    float e[8];
    float ssum = 0.f;
#pragma unroll
    for (int j = 0; j < 8; ++j) {
        e[j] = __expf(l[j] - m);
        ssum += e[j];
    }
    __syncthreads();
    red[kg][pix] = ssum;
    __syncthreads();
    ssum = 0.f;
#pragma unroll
    for (int g = 0; g < 8; ++g) ssum += red[g][pix];
    float si = 1.0f / ssum;

    float* sp = sa + (size_t)n * KK * PP + (size_t)(kg * 8) * PP + p0 + pix;
#pragma unroll
    for (int j = 0; j < 8; ++j) sp[(size_t)j * PP] = e[j] * si;
}

// ---------------- S[n][k] = sum_p sa ----------------
__global__ void k_srow(const float* __restrict__ sa, float* __restrict__ S) {
    int r = blockIdx.x * 4 + (threadIdx.x >> 6);
    int lane = threadIdx.x & 63;
    const float* sp = sa + (size_t)r * PP + lane;
    float s = 0.f;
#pragma unroll
    for (int i = 0; i < PP / 64; ++i) s += sp[i * 64];
#pragma unroll
    for (int off = 32; off > 0; off >>= 1) s += __shfl_xor(s, off);
    if (lane == 0) S[r] = s;
}

// ---------------- vlad[n][k][c] = sum_p sa*xnorm - S*cent ----------------
// grid: N*8 blocks (full K=64 x 64-wide C tile), 1024 threads = 4 P-groups x 256
__global__ void __launch_bounds__(1024) k_vlad(
        const float* __restrict__ x, const float* __restrict__ sa,
        const float* __restrict__ inv_n, const float* __restrict__ S,
        const float* __restrict__ cent, float* __restrict__ vlad) {
    int n = blockIdx.x >> 3;
    int c0 = (blockIdx.x & 7) << 6;
    int tid = threadIdx.x;
    int pg = tid >> 8;            // 0..3 p-group
    int t = tid & 255;
    int kq = (t & 15) << 2;
    int cq = (t >> 4) << 2;

    // group pg owns lds[pg*2*32*68 .. ): sa tile then x tile, each [32][68]
    __shared__ float lds[4 * 2 * 32 * 68];   // 69632 bytes
    float* sa_s = lds + pg * (2 * 32 * 68);
    float* x_s  = sa_s + 32 * 68;

    float acc[4][4] = {};
    const float* xb = x + ((size_t)n * CC + c0) * PP;
    const float* sb = sa + (size_t)n * KK * PP;
    const float* ib = inv_n + n * PP;
    int pbase = pg << 8;          // 256 pixels per group

    for (int pt = 0; pt < 256; pt += 32) {
        int p0 = pbase + pt;
        __syncthreads();
        for (int i = t; i < 2048; i += 256) {
            int k = i >> 5, p = i & 31;
            sa_s[p * 68 + k] = sb[(size_t)k * PP + p0 + p];
        }
        for (int i = t; i < 2048; i += 256) {
            int c = i >> 5, p = i & 31;
            x_s[p * 68 + c] = xb[(size_t)c * PP + p0 + p] * ib[p0 + p];
        }
        __syncthreads();
#pragma unroll 4
        for (int p = 0; p < 32; ++p) {
            float4 a = *(const float4*)&sa_s[p * 68 + kq];
            float4 bb = *(const float4*)&x_s[p * 68 + cq];
            float av[4] = {a.x, a.y, a.z, a.w};
            float bv[4] = {bb.x, bb.y, bb.z, bb.w};
#pragma unroll
            for (int i = 0; i < 4; ++i)
#pragma unroll
                for (int j = 0; j < 4; ++j)
                    acc[i][j] = fmaf(av[i], bv[j], acc[i][j]);
        }
    }

    // cross-group reduction: groups 1..3 dump to LDS, group 0 sums + epilogue
    __syncthreads();
    if (pg > 0) {
        float* r = lds + (size_t)(pg - 1) * 4096 + t * 16;
#pragma unroll
        for (int i = 0; i < 4; ++i)
#pragma unroll
            for (int j = 0; j < 4; ++j) r[i * 4 + j] = acc[i][j];
    }
    __syncthreads();
    if (pg == 0) {
#pragma unroll
        for (int g = 0; g < 3; ++g) {
            const float* r = lds + (size_t)g * 4096 + t * 16;
#pragma unroll
            for (int i = 0; i < 4; ++i)
#pragma unroll
                for (int j = 0; j < 4; ++j) acc[i][j] += r[i * 4 + j];
        }
#pragma unroll
        for (int kk = 0; kk < 4; ++kk) {
            float sv = S[n * KK + kq + kk];
            const float* cp = &cent[(size_t)(kq + kk) * CC + c0 + cq];
            float4 cv = *(const float4*)cp;
            float4 o;
            o.x = fmaf(-sv, cv.x, acc[kk][0]);
            o.y = fmaf(-sv, cv.y, acc[kk][1]);
            o.z = fmaf(-sv, cv.z, acc[kk][2]);
            o.w = fmaf(-sv, cv.w, acc[kk][3]);
            *(float4*)&vlad[((size_t)n * KK + kq + kk) * CC + c0 + cq] = o;
        }
    }
}

// ---------------- per-row (n,k) sumsq + inv norm ----------------
__global__ void k_rownorm(const float* __restrict__ vlad, float* __restrict__ rinv,
                          float* __restrict__ rsq) {
    int r = blockIdx.x * 4 + (threadIdx.x >> 6);
    int lane = threadIdx.x & 63;
    const float* vp = vlad + (size_t)r * CC + lane;
    float s = 0.f;
#pragma unroll
    for (int i = 0; i < CC / 64; ++i) {
        float v = vp[i * 64];
        s = fmaf(v, v, s);
    }
#pragma unroll
    for (int off = 32; off > 0; off >>= 1) s += __shfl_xor(s, off);
    if (lane == 0) {
        float iv = 1.0f / fmaxf(sqrtf(s), EPS);
        rinv[r] = iv;
        rsq[r] = s * iv * iv;
    }
}

// ---------------- per-n total inverse norm ----------------
__global__ void k_tot(const float* __restrict__ rsq, float* __restrict__ tinv) {
    int n = blockIdx.x;
    int lane = threadIdx.x;   // 64 threads
    float s = rsq[n * KK + lane];
#pragma unroll
    for (int off = 32; off > 0; off >>= 1) s += __shfl_xor(s, off);
    if (lane == 0) tinv[n] = 1.0f / fmaxf(sqrtf(s), EPS);
}

// ---------------- final scale ----------------
__global__ void k_final(const float* __restrict__ vlad, const float* __restrict__ rinv,
                        const float* __restrict__ tinv, float* __restrict__ out) {
    size_t i4 = (size_t)blockIdx.x * 256 + threadIdx.x;   // over 262144 float4s
    float4 v = ((const float4*)vlad)[i4];
    int row = (int)(i4 >> 7);
    int n = row >> 6;
    float sc = rinv[row] * tinv[n];
    float4 o{v.x * sc, v.y * sc, v.z * sc, v.w * sc};
    ((float4*)out)[i4] = o;
}

extern "C" void kernel_launch(void* const* d_in, const int* in_sizes, int n_in,
                              void* d_out, int out_size, void* d_ws, size_t ws_size,
                              hipStream_t stream) {
    const float* x    = (const float*)d_in[0];
    const float* w    = (const float*)d_in[1];
    const float* bias = (const float*)d_in[2];
    const float* cent = (const float*)d_in[3];
    float* ws = (float*)d_ws;

    float* inv_n = ws;                          // 32768
    float* sa    = inv_n + NN * PP;             // 2097152
    float* S     = sa + (size_t)NN * KK * PP;   // 2048
    float* vlad  = S + NN * KK;                 // 1048576
    float* rinv  = vlad + (size_t)NN * KK * CC; // 2048
    float* rsq   = rinv + NN * KK;              // 2048
    float* tinv  = rsq + NN * KK;               // 32
    float* wT    = tinv + NN;                   // 32768

    float* out = (float*)d_out;

    k_transpose_w<<<dim3(128), dim3(256), 0, stream>>>(w, wT);
    k_softmax<<<dim3(NN * 16), dim3(512), 0, stream>>>(x, wT, bias, inv_n, sa);
    k_srow<<<dim3(NN * KK / 4), dim3(256), 0, stream>>>(sa, S);
    k_vlad<<<dim3(NN * 8), dim3(1024), 0, stream>>>(x, sa, inv_n, S, cent, vlad);
    k_rownorm<<<dim3(NN * KK / 4), dim3(256), 0, stream>>>(vlad, rinv, rsq);
    k_tot<<<dim3(NN), dim3(64), 0, stream>>>(rsq, tinv);
    k_final<<<dim3(1024), dim3(256), 0, stream>>>(vlad, rinv, tinv, out);
}

// Round 3
// 110.418 us; speedup vs baseline: 2.6686x; 1.0600x over previous
//
#include <hip/hip_runtime.h>
#include <math.h>

#define NN 32
#define CC 512
#define PP 1024   // H*W
#define KK 64
static constexpr float EPS = 1e-12f;

// ---------------- transpose conv_w [K][C] -> wT [C][K] ----------------
__global__ void k_transpose_w(const float* __restrict__ w, float* __restrict__ wT) {
    int i = blockIdx.x * 256 + threadIdx.x;   // over C*K = 32768
    if (i >= CC * KK) return;
    int c = i >> 6, k = i & 63;
    wT[i] = w[k * CC + c];
}

// ---------------- fused pixnorm + logits + softmax over K -> sa [N][K][P] ----------------
// grid: N*16 blocks (64 pixels each), 512 threads (8 waves; wave kg owns k = kg*8..kg*8+7)
// x and w staged through LDS in 64-channel chunks with register prefetch.
// Per-pixel sumsq accumulated redundantly by every thread (fuses the pixnorm pass).
__global__ void __launch_bounds__(512) k_softmax(
        const float* __restrict__ x, const float* __restrict__ wT,
        const float* __restrict__ bias, float* __restrict__ inv_n,
        float* __restrict__ sa) {
    int b = blockIdx.x;
    int n = b >> 4;
    int p0 = (b & 15) << 6;
    int tid = threadIdx.x;
    int pix = tid & 63;
    int cc  = tid >> 6;                                          // 0..7
    int kg  = __builtin_amdgcn_readfirstlane(tid >> 6);          // wave-uniform 0..7

    __shared__ float x_s[64 * 64];   // [c][pix]
    __shared__ float w_s[64 * 64];   // [c][k]
    __shared__ float red[8][64];

    const float* xb = x + ((size_t)n * CC) * PP + p0 + pix;

    float b8[8];
#pragma unroll
    for (int j = 0; j < 8; ++j) b8[j] = bias[kg * 8 + j];

    float acc[8] = {};
    float sumsq = 0.f;

    // prefetch chunk 0 into registers
    float xr[8];
    float4 wr0, wr1;
    {
#pragma unroll
        for (int i = 0; i < 8; ++i) xr[i] = xb[(size_t)(cc * 8 + i) * PP];
        const float4* wc = (const float4*)wT + (size_t)tid * 2;
        wr0 = wc[0]; wr1 = wc[1];
    }

    for (int ct = 0; ct < 8; ++ct) {
        __syncthreads();   // previous chunk's compute done; LDS reusable
#pragma unroll
        for (int i = 0; i < 8; ++i) x_s[(cc * 8 + i) * 64 + pix] = xr[i];
        ((float4*)w_s)[tid * 2]     = wr0;
        ((float4*)w_s)[tid * 2 + 1] = wr1;
        if (ct < 7) {
            int c0 = (ct + 1) * 64;
#pragma unroll
            for (int i = 0; i < 8; ++i) xr[i] = xb[(size_t)(c0 + cc * 8 + i) * PP];
            const float4* wc = (const float4*)(wT + (size_t)c0 * 64) + (size_t)tid * 2;
            wr0 = wc[0]; wr1 = wc[1];
        }
        __syncthreads();   // this chunk staged
#pragma unroll 8
        for (int c = 0; c < 64; ++c) {
            float xv = x_s[c * 64 + pix];
            sumsq = fmaf(xv, xv, sumsq);
            const float4* wv4 = (const float4*)&w_s[c * 64 + kg * 8];
            float4 w0 = wv4[0], w1 = wv4[1];
            acc[0] = fmaf(w0.x, xv, acc[0]);
            acc[1] = fmaf(w0.y, xv, acc[1]);
            acc[2] = fmaf(w0.z, xv, acc[2]);
            acc[3] = fmaf(w0.w, xv, acc[3]);
            acc[4] = fmaf(w1.x, xv, acc[4]);
            acc[5] = fmaf(w1.y, xv, acc[5]);
            acc[6] = fmaf(w1.z, xv, acc[6]);
            acc[7] = fmaf(w1.w, xv, acc[7]);
        }
    }

    float inv = 1.0f / fmaxf(sqrtf(sumsq), EPS);
    if (kg == 0) inv_n[n * PP + p0 + pix] = inv;

    float l[8];
    float m = -1e30f;
#pragma unroll
    for (int j = 0; j < 8; ++j) {
        l[j] = fmaf(acc[j], inv, b8[j]);
        m = fmaxf(m, l[j]);
    }

    __syncthreads();
    red[kg][pix] = m;
    __syncthreads();
    m = -1e30f;
#pragma unroll
    for (int g = 0; g < 8; ++g) m = fmaxf(m, red[g][pix]);

    float e[8];
    float ssum = 0.f;
#pragma unroll
    for (int j = 0; j < 8; ++j) {
        e[j] = __expf(l[j] - m);
        ssum += e[j];
    }
    __syncthreads();
    red[kg][pix] = ssum;
    __syncthreads();
    ssum = 0.f;
#pragma unroll
    for (int g = 0; g < 8; ++g) ssum += red[g][pix];
    float si = 1.0f / ssum;

    float* sp = sa + (size_t)n * KK * PP + (size_t)(kg * 8) * PP + p0 + pix;
#pragma unroll
    for (int j = 0; j < 8; ++j) sp[(size_t)j * PP] = e[j] * si;
}

// ---------------- S[n][k] = sum_p sa ----------------
__global__ void k_srow(const float* __restrict__ sa, float* __restrict__ S) {
    int r = blockIdx.x * 4 + (threadIdx.x >> 6);
    int lane = threadIdx.x & 63;
    const float* sp = sa + (size_t)r * PP + lane;
    float s = 0.f;
#pragma unroll
    for (int i = 0; i < PP / 64; ++i) s += sp[i * 64];
#pragma unroll
    for (int off = 32; off > 0; off >>= 1) s += __shfl_xor(s, off);
    if (lane == 0) S[r] = s;
}

// ---------------- vlad[n][k][c] = sum_p sa*xnorm - S*cent ----------------
// grid: N*8 blocks (full K=64 x 64-wide C tile), 1024 threads = 4 P-groups x 256
__global__ void __launch_bounds__(1024) k_vlad(
        const float* __restrict__ x, const float* __restrict__ sa,
        const float* __restrict__ inv_n, const float* __restrict__ S,
        const float* __restrict__ cent, float* __restrict__ vlad) {
    int n = blockIdx.x >> 3;
    int c0 = (blockIdx.x & 7) << 6;
    int tid = threadIdx.x;
    int pg = tid >> 8;            // 0..3 p-group
    int t = tid & 255;
    int kq = (t & 15) << 2;
    int cq = (t >> 4) << 2;

    __shared__ float lds[4 * 2 * 32 * 68];   // 69632 bytes
    float* sa_s = lds + pg * (2 * 32 * 68);
    float* x_s  = sa_s + 32 * 68;

    float acc[4][4] = {};
    const float* xb = x + ((size_t)n * CC + c0) * PP;
    const float* sb = sa + (size_t)n * KK * PP;
    const float* ib = inv_n + n * PP;
    int pbase = pg << 8;          // 256 pixels per group

    for (int pt = 0; pt < 256; pt += 32) {
        int p0 = pbase + pt;
        __syncthreads();
        for (int i = t; i < 2048; i += 256) {
            int k = i >> 5, p = i & 31;
            sa_s[p * 68 + k] = sb[(size_t)k * PP + p0 + p];
        }
        for (int i = t; i < 2048; i += 256) {
            int c = i >> 5, p = i & 31;
            x_s[p * 68 + c] = xb[(size_t)c * PP + p0 + p] * ib[p0 + p];
        }
        __syncthreads();
#pragma unroll 4
        for (int p = 0; p < 32; ++p) {
            float4 a = *(const float4*)&sa_s[p * 68 + kq];
            float4 bb = *(const float4*)&x_s[p * 68 + cq];
            float av[4] = {a.x, a.y, a.z, a.w};
            float bv[4] = {bb.x, bb.y, bb.z, bb.w};
#pragma unroll
            for (int i = 0; i < 4; ++i)
#pragma unroll
                for (int j = 0; j < 4; ++j)
                    acc[i][j] = fmaf(av[i], bv[j], acc[i][j]);
        }
    }

    __syncthreads();
    if (pg > 0) {
        float* r = lds + (size_t)(pg - 1) * 4096 + t * 16;
#pragma unroll
        for (int i = 0; i < 4; ++i)
#pragma unroll
            for (int j = 0; j < 4; ++j) r[i * 4 + j] = acc[i][j];
    }
    __syncthreads();
    if (pg == 0) {
#pragma unroll
        for (int g = 0; g < 3; ++g) {
            const float* r = lds + (size_t)g * 4096 + t * 16;
#pragma unroll
            for (int i = 0; i < 4; ++i)
#pragma unroll
                for (int j = 0; j < 4; ++j) acc[i][j] += r[i * 4 + j];
        }
#pragma unroll
        for (int kk = 0; kk < 4; ++kk) {
            float sv = S[n * KK + kq + kk];
            const float* cp = &cent[(size_t)(kq + kk) * CC + c0 + cq];
            float4 cv = *(const float4*)cp;
            float4 o;
            o.x = fmaf(-sv, cv.x, acc[kk][0]);
            o.y = fmaf(-sv, cv.y, acc[kk][1]);
            o.z = fmaf(-sv, cv.z, acc[kk][2]);
            o.w = fmaf(-sv, cv.w, acc[kk][3]);
            *(float4*)&vlad[((size_t)n * KK + kq + kk) * CC + c0 + cq] = o;
        }
    }
}

// ---------------- per-row (n,k) sumsq + inv norm ----------------
__global__ void k_rownorm(const float* __restrict__ vlad, float* __restrict__ rinv,
                          float* __restrict__ rsq) {
    int r = blockIdx.x * 4 + (threadIdx.x >> 6);
    int lane = threadIdx.x & 63;
    const float* vp = vlad + (size_t)r * CC + lane;
    float s = 0.f;
#pragma unroll
    for (int i = 0; i < CC / 64; ++i) {
        float v = vp[i * 64];
        s = fmaf(v, v, s);
    }
#pragma unroll
    for (int off = 32; off > 0; off >>= 1) s += __shfl_xor(s, off);
    if (lane == 0) {
        float iv = 1.0f / fmaxf(sqrtf(s), EPS);
        rinv[r] = iv;
        rsq[r] = s * iv * iv;
    }
}

// ---------------- per-n total inverse norm ----------------
__global__ void k_tot(const float* __restrict__ rsq, float* __restrict__ tinv) {
    int n = blockIdx.x;
    int lane = threadIdx.x;   // 64 threads
    float s = rsq[n * KK + lane];
#pragma unroll
    for (int off = 32; off > 0; off >>= 1) s += __shfl_xor(s, off);
    if (lane == 0) tinv[n] = 1.0f / fmaxf(sqrtf(s), EPS);
}

// ---------------- final scale ----------------
__global__ void k_final(const float* __restrict__ vlad, const float* __restrict__ rinv,
                        const float* __restrict__ tinv, float* __restrict__ out) {
    size_t i4 = (size_t)blockIdx.x * 256 + threadIdx.x;   // over 262144 float4s
    float4 v = ((const float4*)vlad)[i4];
    int row = (int)(i4 >> 7);
    int n = row >> 6;
    float sc = rinv[row] * tinv[n];
    float4 o{v.x * sc, v.y * sc, v.z * sc, v.w * sc};
    ((float4*)out)[i4] = o;
}

extern "C" void kernel_launch(void* const* d_in, const int* in_sizes, int n_in,
                              void* d_out, int out_size, void* d_ws, size_t ws_size,
                              hipStream_t stream) {
    const float* x    = (const float*)d_in[0];
    const float* w    = (const float*)d_in[1];
    const float* bias = (const float*)d_in[2];
    const float* cent = (const float*)d_in[3];
    float* ws = (float*)d_ws;

    float* inv_n = ws;                          // 32768
    float* sa    = inv_n + NN * PP;             // 2097152
    float* S     = sa + (size_t)NN * KK * PP;   // 2048
    float* vlad  = S + NN * KK;                 // 1048576
    float* rinv  = vlad + (size_t)NN * KK * CC; // 2048
    float* rsq   = rinv + NN * KK;              // 2048
    float* tinv  = rsq + NN * KK;               // 32
    float* wT    = tinv + NN;                   // 32768

    float* out = (float*)d_out;

    k_transpose_w<<<dim3(128), dim3(256), 0, stream>>>(w, wT);
    k_softmax<<<dim3(NN * 16), dim3(512), 0, stream>>>(x, wT, bias, inv_n, sa);
    k_srow<<<dim3(NN * KK / 4), dim3(256), 0, stream>>>(sa, S);
    k_vlad<<<dim3(NN * 8), dim3(1024), 0, stream>>>(x, sa, inv_n, S, cent, vlad);
    k_rownorm<<<dim3(NN * KK / 4), dim3(256), 0, stream>>>(vlad, rinv, rsq);
    k_tot<<<dim3(NN), dim3(64), 0, stream>>>(rsq, tinv);
    k_final<<<dim3(1024), dim3(256), 0, stream>>>(vlad, rinv, tinv, out);
}

// Round 4
// 105.097 us; speedup vs baseline: 2.8037x; 1.0506x over previous
//
#include <hip/hip_runtime.h>
#include <math.h>

#define NN 32
#define CC 512
#define PP 1024   // H*W
#define KK 64
static constexpr float EPS = 1e-12f;

// ---------------- transpose conv_w [K][C] -> wT [C][K] ----------------
__global__ void k_transpose_w(const float* __restrict__ w, float* __restrict__ wT) {
    int i = blockIdx.x * 256 + threadIdx.x;   // over C*K = 32768
    if (i >= CC * KK) return;
    int c = i >> 6, k = i & 63;
    wT[i] = w[k * CC + c];
}

// ---------------- fused pixnorm + logits + softmax over K -> sa [N][K][P] ----------------
// grid: N*16 blocks (64 pixels), 512 threads.
// Thread tile: 4 px x 4 k, 2 c-halves (256 c each) merged via LDS at the end.
// pg = tid&15 (pixel quad), rr = tid>>4 (staging row 0..31), kg = rr&15 (k quad),
// ch = tid>>8 (c half). sumsq accumulated during staging (each element once).
__global__ void __launch_bounds__(512, 4) k_softmax(
        const float* __restrict__ x, const float* __restrict__ wT,
        const float* __restrict__ bias, float* __restrict__ inv_n,
        float* __restrict__ sa) {
    int b = blockIdx.x;
    int n = b >> 4;
    int p0 = (b & 15) << 6;
    int tid = threadIdx.x;
    int pg = tid & 15;
    int rr = tid >> 4;          // 0..31
    int kg = rr & 15;
    int ch = tid >> 8;          // 0..1 (wave-uniform)

    __shared__ __align__(16) float x_s[2][64][68];   // [buf][c][px] 34816 B
    __shared__ __align__(16) float w_s[2][64][68];   // [buf][c][k]  34816 B
    __shared__ __align__(16) float red2[32][64];     // sumsq partials 8 KB
    __shared__ __align__(16) float redI[64];

    const float* xb = x + ((size_t)n * CC) * PP + p0;

    float4 b4 = ((const float4*)bias)[kg];

    float acc[4][4] = {};
    float ssq0 = 0.f, ssq1 = 0.f, ssq2 = 0.f, ssq3 = 0.f;

    float4 xr[2][2], wr[2][2];
    // prefetch iter 0: buffers hold chunks it (buf0) and it+4 (buf1)
#pragma unroll
    for (int h = 0; h < 2; ++h)
#pragma unroll
        for (int q = 0; q < 2; ++q) {
            int c = (h * 4) * 64 + q * 32 + rr;
            xr[h][q] = *(const float4*)&xb[(size_t)c * PP + (pg << 2)];
            wr[h][q] = *(const float4*)&wT[(c << 6) + (pg << 2)];
        }

    const float* xsp = &x_s[ch][0][pg << 2];
    const float* wsp = &w_s[ch][0][kg << 2];

    for (int it = 0; it < 4; ++it) {
        __syncthreads();
#pragma unroll
        for (int h = 0; h < 2; ++h)
#pragma unroll
            for (int q = 0; q < 2; ++q) {
                int cl = q * 32 + rr;
                *(float4*)&x_s[h][cl][pg << 2] = xr[h][q];
                *(float4*)&w_s[h][cl][pg << 2] = wr[h][q];
                ssq0 = fmaf(xr[h][q].x, xr[h][q].x, ssq0);
                ssq1 = fmaf(xr[h][q].y, xr[h][q].y, ssq1);
                ssq2 = fmaf(xr[h][q].z, xr[h][q].z, ssq2);
                ssq3 = fmaf(xr[h][q].w, xr[h][q].w, ssq3);
            }
        if (it < 3) {
#pragma unroll
            for (int h = 0; h < 2; ++h)
#pragma unroll
                for (int q = 0; q < 2; ++q) {
                    int c = (it + 1 + h * 4) * 64 + q * 32 + rr;
                    xr[h][q] = *(const float4*)&xb[(size_t)c * PP + (pg << 2)];
                    wr[h][q] = *(const float4*)&wT[(c << 6) + (pg << 2)];
                }
        }
        __syncthreads();
#pragma unroll 8
        for (int c = 0; c < 64; ++c) {
            float4 xv = *(const float4*)(xsp + c * 68);
            float4 wv = *(const float4*)(wsp + c * 68);
            acc[0][0] = fmaf(xv.x, wv.x, acc[0][0]);
            acc[0][1] = fmaf(xv.x, wv.y, acc[0][1]);
            acc[0][2] = fmaf(xv.x, wv.z, acc[0][2]);
            acc[0][3] = fmaf(xv.x, wv.w, acc[0][3]);
            acc[1][0] = fmaf(xv.y, wv.x, acc[1][0]);
            acc[1][1] = fmaf(xv.y, wv.y, acc[1][1]);
            acc[1][2] = fmaf(xv.y, wv.z, acc[1][2]);
            acc[1][3] = fmaf(xv.y, wv.w, acc[1][3]);
            acc[2][0] = fmaf(xv.z, wv.x, acc[2][0]);
            acc[2][1] = fmaf(xv.z, wv.y, acc[2][1]);
            acc[2][2] = fmaf(xv.z, wv.z, acc[2][2]);
            acc[2][3] = fmaf(xv.z, wv.w, acc[2][3]);
            acc[3][0] = fmaf(xv.w, wv.x, acc[3][0]);
            acc[3][1] = fmaf(xv.w, wv.y, acc[3][1]);
            acc[3][2] = fmaf(xv.w, wv.z, acc[3][2]);
            acc[3][3] = fmaf(xv.w, wv.w, acc[3][3]);
        }
    }

    // ---- epilogue ----
    __syncthreads();
    *(float4*)&red2[rr][pg << 2] = make_float4(ssq0, ssq1, ssq2, ssq3);
    float* dump = (float*)x_s;           // x_s free now: 256 thr x 16 floats
    if (ch == 1) {
        float* d = dump + (tid - 256) * 16;
#pragma unroll
        for (int i = 0; i < 4; ++i)
            *(float4*)&d[i * 4] = make_float4(acc[i][0], acc[i][1], acc[i][2], acc[i][3]);
    }
    __syncthreads();
    if (tid < 64) {
        float s = 0.f;
#pragma unroll
        for (int r = 0; r < 32; ++r) s += red2[r][tid];
        float inv = 1.0f / fmaxf(sqrtf(s), EPS);
        inv_n[n * PP + p0 + tid] = inv;
        redI[tid] = inv;
    }
    __syncthreads();

    float* redA = &w_s[0][0][0];         // w_s free now
    float* redS = redA + 256;
    float l[4][4], mx[4], e[4][4], sk[4];
    int wv = tid >> 6;                   // wave id 0..3 (for ch==0)
    if (ch == 0) {
        const float* d = dump + tid * 16;
#pragma unroll
        for (int i = 0; i < 4; ++i)
#pragma unroll
            for (int j = 0; j < 4; ++j) acc[i][j] += d[i * 4 + j];
        float4 iv = *(const float4*)&redI[pg << 2];
        float ivp[4] = {iv.x, iv.y, iv.z, iv.w};
#pragma unroll
        for (int p = 0; p < 4; ++p) {
            mx[p] = -1e30f;
#pragma unroll
            for (int k = 0; k < 4; ++k) {
                l[p][k] = fmaf(acc[p][k], ivp[p], ((const float*)&b4)[k]);
                mx[p] = fmaxf(mx[p], l[p][k]);
            }
        }
#pragma unroll
        for (int p = 0; p < 4; ++p) {
            mx[p] = fmaxf(mx[p], __shfl_xor(mx[p], 16));
            mx[p] = fmaxf(mx[p], __shfl_xor(mx[p], 32));
        }
        if ((tid & 48) == 0)
            *(float4*)&redA[wv * 64 + (pg << 2)] = make_float4(mx[0], mx[1], mx[2], mx[3]);
    }
    __syncthreads();
    if (ch == 0) {
        float4 a0 = *(const float4*)&redA[0 * 64 + (pg << 2)];
        float4 a1 = *(const float4*)&redA[1 * 64 + (pg << 2)];
        float4 a2 = *(const float4*)&redA[2 * 64 + (pg << 2)];
        float4 a3 = *(const float4*)&redA[3 * 64 + (pg << 2)];
        mx[0] = fmaxf(fmaxf(a0.x, a1.x), fmaxf(a2.x, a3.x));
        mx[1] = fmaxf(fmaxf(a0.y, a1.y), fmaxf(a2.y, a3.y));
        mx[2] = fmaxf(fmaxf(a0.z, a1.z), fmaxf(a2.z, a3.z));
        mx[3] = fmaxf(fmaxf(a0.w, a1.w), fmaxf(a2.w, a3.w));
#pragma unroll
        for (int p = 0; p < 4; ++p) {
            sk[p] = 0.f;
#pragma unroll
            for (int k = 0; k < 4; ++k) {
                e[p][k] = __expf(l[p][k] - mx[p]);
                sk[p] += e[p][k];
            }
            sk[p] += __shfl_xor(sk[p], 16);
            sk[p] += __shfl_xor(sk[p], 32);
        }
        if ((tid & 48) == 0)
            *(float4*)&redS[wv * 64 + (pg << 2)] = make_float4(sk[0], sk[1], sk[2], sk[3]);
    }
    __syncthreads();
    if (ch == 0) {
        float4 a0 = *(const float4*)&redS[0 * 64 + (pg << 2)];
        float4 a1 = *(const float4*)&redS[1 * 64 + (pg << 2)];
        float4 a2 = *(const float4*)&redS[2 * 64 + (pg << 2)];
        float4 a3 = *(const float4*)&redS[3 * 64 + (pg << 2)];
        float si[4];
        si[0] = 1.0f / (a0.x + a1.x + a2.x + a3.x);
        si[1] = 1.0f / (a0.y + a1.y + a2.y + a3.y);
        si[2] = 1.0f / (a0.z + a1.z + a2.z + a3.z);
        si[3] = 1.0f / (a0.w + a1.w + a2.w + a3.w);
#pragma unroll
        for (int k = 0; k < 4; ++k) {
            float4 o;
            o.x = e[0][k] * si[0];
            o.y = e[1][k] * si[1];
            o.z = e[2][k] * si[2];
            o.w = e[3][k] * si[3];
            *(float4*)&sa[((size_t)n * KK + (kg << 2) + k) * PP + p0 + (pg << 2)] = o;
        }
    }
}

// ---------------- S[n][k] = sum_p sa ----------------
__global__ void k_srow(const float* __restrict__ sa, float* __restrict__ S) {
    int r = blockIdx.x * 4 + (threadIdx.x >> 6);
    int lane = threadIdx.x & 63;
    const float* sp = sa + (size_t)r * PP + lane;
    float s = 0.f;
#pragma unroll
    for (int i = 0; i < PP / 64; ++i) s += sp[i * 64];
#pragma unroll
    for (int off = 32; off > 0; off >>= 1) s += __shfl_xor(s, off);
    if (lane == 0) S[r] = s;
}

// ---------------- vlad[n][k][c] = sum_p sa*xnorm - S*cent ----------------
// grid: N*8 blocks (full K=64 x 64-wide C tile), 1024 threads = 4 P-groups x 256
__global__ void __launch_bounds__(1024) k_vlad(
        const float* __restrict__ x, const float* __restrict__ sa,
        const float* __restrict__ inv_n, const float* __restrict__ S,
        const float* __restrict__ cent, float* __restrict__ vlad) {
    int n = blockIdx.x >> 3;
    int c0 = (blockIdx.x & 7) << 6;
    int tid = threadIdx.x;
    int pg = tid >> 8;            // 0..3 p-group
    int t = tid & 255;
    int kq = (t & 15) << 2;
    int cq = (t >> 4) << 2;

    __shared__ float lds[4 * 2 * 32 * 68];   // 69632 bytes
    float* sa_s = lds + pg * (2 * 32 * 68);
    float* x_s  = sa_s + 32 * 68;

    float acc[4][4] = {};
    const float* xb = x + ((size_t)n * CC + c0) * PP;
    const float* sb = sa + (size_t)n * KK * PP;
    const float* ib = inv_n + n * PP;
    int pbase = pg << 8;          // 256 pixels per group

    for (int pt = 0; pt < 256; pt += 32) {
        int p0 = pbase + pt;
        __syncthreads();
        for (int i = t; i < 2048; i += 256) {
            int k = i >> 5, p = i & 31;
            sa_s[p * 68 + k] = sb[(size_t)k * PP + p0 + p];
        }
        for (int i = t; i < 2048; i += 256) {
            int c = i >> 5, p = i & 31;
            x_s[p * 68 + c] = xb[(size_t)c * PP + p0 + p] * ib[p0 + p];
        }
        __syncthreads();
#pragma unroll 4
        for (int p = 0; p < 32; ++p) {
            float4 a = *(const float4*)&sa_s[p * 68 + kq];
            float4 bb = *(const float4*)&x_s[p * 68 + cq];
            float av[4] = {a.x, a.y, a.z, a.w};
            float bv[4] = {bb.x, bb.y, bb.z, bb.w};
#pragma unroll
            for (int i = 0; i < 4; ++i)
#pragma unroll
                for (int j = 0; j < 4; ++j)
                    acc[i][j] = fmaf(av[i], bv[j], acc[i][j]);
        }
    }

    __syncthreads();
    if (pg > 0) {
        float* r = lds + (size_t)(pg - 1) * 4096 + t * 16;
#pragma unroll
        for (int i = 0; i < 4; ++i)
#pragma unroll
            for (int j = 0; j < 4; ++j) r[i * 4 + j] = acc[i][j];
    }
    __syncthreads();
    if (pg == 0) {
#pragma unroll
        for (int g = 0; g < 3; ++g) {
            const float* r = lds + (size_t)g * 4096 + t * 16;
#pragma unroll
            for (int i = 0; i < 4; ++i)
#pragma unroll
                for (int j = 0; j < 4; ++j) acc[i][j] += r[i * 4 + j];
        }
#pragma unroll
        for (int kk = 0; kk < 4; ++kk) {
            float sv = S[n * KK + kq + kk];
            const float* cp = &cent[(size_t)(kq + kk) * CC + c0 + cq];
            float4 cv = *(const float4*)cp;
            float4 o;
            o.x = fmaf(-sv, cv.x, acc[kk][0]);
            o.y = fmaf(-sv, cv.y, acc[kk][1]);
            o.z = fmaf(-sv, cv.z, acc[kk][2]);
            o.w = fmaf(-sv, cv.w, acc[kk][3]);
            *(float4*)&vlad[((size_t)n * KK + kq + kk) * CC + c0 + cq] = o;
        }
    }
}

// ---------------- per-row (n,k) sumsq + inv norm ----------------
__global__ void k_rownorm(const float* __restrict__ vlad, float* __restrict__ rinv,
                          float* __restrict__ rsq) {
    int r = blockIdx.x * 4 + (threadIdx.x >> 6);
    int lane = threadIdx.x & 63;
    const float* vp = vlad + (size_t)r * CC + lane;
    float s = 0.f;
#pragma unroll
    for (int i = 0; i < CC / 64; ++i) {
        float v = vp[i * 64];
        s = fmaf(v, v, s);
    }
#pragma unroll
    for (int off = 32; off > 0; off >>= 1) s += __shfl_xor(s, off);
    if (lane == 0) {
        float iv = 1.0f / fmaxf(sqrtf(s), EPS);
        rinv[r] = iv;
        rsq[r] = s * iv * iv;
    }
}

// ---------------- per-n total inverse norm ----------------
__global__ void k_tot(const float* __restrict__ rsq, float* __restrict__ tinv) {
    int n = blockIdx.x;
    int lane = threadIdx.x;   // 64 threads
    float s = rsq[n * KK + lane];
#pragma unroll
    for (int off = 32; off > 0; off >>= 1) s += __shfl_xor(s, off);
    if (lane == 0) tinv[n] = 1.0f / fmaxf(sqrtf(s), EPS);
}

// ---------------- final scale ----------------
__global__ void k_final(const float* __restrict__ vlad, const float* __restrict__ rinv,
                        const float* __restrict__ tinv, float* __restrict__ out) {
    size_t i4 = (size_t)blockIdx.x * 256 + threadIdx.x;   // over 262144 float4s
    float4 v = ((const float4*)vlad)[i4];
    int row = (int)(i4 >> 7);
    int n = row >> 6;
    float sc = rinv[row] * tinv[n];
    float4 o{v.x * sc, v.y * sc, v.z * sc, v.w * sc};
    ((float4*)out)[i4] = o;
}

extern "C" void kernel_launch(void* const* d_in, const int* in_sizes, int n_in,
                              void* d_out, int out_size, void* d_ws, size_t ws_size,
                              hipStream_t stream) {
    const float* x    = (const float*)d_in[0];
    const float* w    = (const float*)d_in[1];
    const float* bias = (const float*)d_in[2];
    const float* cent = (const float*)d_in[3];
    float* ws = (float*)d_ws;

    float* inv_n = ws;                          // 32768
    float* sa    = inv_n + NN * PP;             // 2097152
    float* S     = sa + (size_t)NN * KK * PP;   // 2048
    float* vlad  = S + NN * KK;                 // 1048576
    float* rinv  = vlad + (size_t)NN * KK * CC; // 2048
    float* rsq   = rinv + NN * KK;              // 2048
    float* tinv  = rsq + NN * KK;               // 32
    float* wT    = tinv + NN;                   // 32768

    float* out = (float*)d_out;

    k_transpose_w<<<dim3(128), dim3(256), 0, stream>>>(w, wT);
    k_softmax<<<dim3(NN * 16), dim3(512), 0, stream>>>(x, wT, bias, inv_n, sa);
    k_srow<<<dim3(NN * KK / 4), dim3(256), 0, stream>>>(sa, S);
    k_vlad<<<dim3(NN * 8), dim3(1024), 0, stream>>>(x, sa, inv_n, S, cent, vlad);
    k_rownorm<<<dim3(NN * KK / 4), dim3(256), 0, stream>>>(vlad, rinv, rsq);
    k_tot<<<dim3(NN), dim3(64), 0, stream>>>(rsq, tinv);
    k_final<<<dim3(1024), dim3(256), 0, stream>>>(vlad, rinv, tinv, out);
}